// Round 1
// baseline (148.743 us; speedup 1.0000x reference)
//
#include <hip/hip_runtime.h>

// EmbeddingDistance: out[b] = 1 - dot(mean_i norm(x1[b,i,:]), mean_j norm(x2[b,j,:]))
// x1, x2: (16, 4096, 256) fp32.  134 MB input read exactly once.
// v2: 16-lanes-per-row norm reduce (4 shfl steps, not 6; 4 ds-ops/4rows, not 24)
//     + double-buffered global loads so the wave always has 8x16B in flight.

constexpr int D = 256;            // embedding dim
constexpr int S = 4096;           // segments (rows) per batch
constexpr int B = 16;             // batches
constexpr int BLOCKS_PER_PAIR = 64;
constexpr int WAVES_PER_BLOCK = 4;              // 256 threads
constexpr int WAVES_PER_PAIR  = BLOCKS_PER_PAIR * WAVES_PER_BLOCK;  // 256
constexpr int ROWS_PER_WAVE   = S / WAVES_PER_PAIR;                 // 16
constexpr int NPAIR = 2 * B;                                        // 32
constexpr int NBLK1 = NPAIR * BLOCKS_PER_PAIR;                      // 2048
constexpr float EPS2 = 1e-16f;    // eps^2 for the norm clamp

// ---- Kernel 1: 4 rows per wave-step. lane = (g<<4)|sub: g = row-in-group,
// sub = dim-slice (16 floats as 4 float4s at float4-index sub, sub+16, ...).
// Per step: 4 coalesced 256B segments per load instr, 4-step 16-lane reduce.
template <bool USE_PARTIALS>
__global__ __launch_bounds__(256) void row_norm_sum_kernel(
    const float* __restrict__ x1, const float* __restrict__ x2,
    float* __restrict__ sums /* USE_PARTIALS ? [NBLK1][D] : [NPAIR][D] */)
{
    const int pair = blockIdx.x / BLOCKS_PER_PAIR;      // 0..31
    const int blk  = blockIdx.x % BLOCKS_PER_PAIR;      // 0..63
    const int w    = threadIdx.x >> 6;                  // 0..3
    const int lane = threadIdx.x & 63;
    const int sub  = lane & 15;                         // dim-slice owner
    const int g    = lane >> 4;                         // row-group 0..3
    const int wv   = blk * WAVES_PER_BLOCK + w;         // 0..255 within pair

    const int batch = pair >> 1;
    const float* __restrict__ src = (pair & 1) ? x2 : x1;
    src += (size_t)batch * S * D;

    // wave owns rows [wv*16, wv*16+16); lane's base: row g, float4 #sub
    const float* __restrict__ lbase =
        src + (size_t)(wv * ROWS_PER_WAVE + g) * D + sub * 4;

    float4 a0 = make_float4(0.f,0.f,0.f,0.f);
    float4 a1 = a0, a2 = a0, a3 = a0;
    float4 va0, va1, va2, va3, vb0, vb1, vb2, vb3;

#define LOADV(v0,v1,v2,v3, i)  do {                     \
    const float* p_ = lbase + (size_t)(i) * 4 * D;      \
    v0 = *(const float4*)(p_ +   0);                    \
    v1 = *(const float4*)(p_ +  64);                    \
    v2 = *(const float4*)(p_ + 128);                    \
    v3 = *(const float4*)(p_ + 192); } while (0)

#define STEPV(v0,v1,v2,v3) do {                                        \
    float ss = v0.x*v0.x + v0.y*v0.y + v0.z*v0.z + v0.w*v0.w           \
             + v1.x*v1.x + v1.y*v1.y + v1.z*v1.z + v1.w*v1.w           \
             + v2.x*v2.x + v2.y*v2.y + v2.z*v2.z + v2.w*v2.w           \
             + v3.x*v3.x + v3.y*v3.y + v3.z*v3.z + v3.w*v3.w;          \
    ss += __shfl_xor(ss, 1, 64);                                       \
    ss += __shfl_xor(ss, 2, 64);                                       \
    ss += __shfl_xor(ss, 4, 64);                                       \
    ss += __shfl_xor(ss, 8, 64);                                       \
    const float sc_ = rsqrtf(fmaxf(ss, EPS2));                         \
    a0.x += v0.x*sc_; a0.y += v0.y*sc_; a0.z += v0.z*sc_; a0.w += v0.w*sc_; \
    a1.x += v1.x*sc_; a1.y += v1.y*sc_; a1.z += v1.z*sc_; a1.w += v1.w*sc_; \
    a2.x += v2.x*sc_; a2.y += v2.y*sc_; a2.z += v2.z*sc_; a2.w += v2.w*sc_; \
    a3.x += v3.x*sc_; a3.y += v3.y*sc_; a3.z += v3.z*sc_; a3.w += v3.w*sc_; \
  } while (0)

    // 4 steps of 4 rows, double-buffered: next step's loads are in flight
    // while the current step reduces.
    LOADV(va0,va1,va2,va3, 0);
    LOADV(vb0,vb1,vb2,vb3, 1);
    STEPV(va0,va1,va2,va3);
    LOADV(va0,va1,va2,va3, 2);
    STEPV(vb0,vb1,vb2,vb3);
    LOADV(vb0,vb1,vb2,vb3, 3);
    STEPV(va0,va1,va2,va3);
    STEPV(vb0,vb1,vb2,vb3);

#undef LOADV
#undef STEPV

    // Combine the 4 row-groups (lanes differing in bits 4,5) — once per wave.
#define GRED(m_)                                                        \
    a0.x += __shfl_xor(a0.x, m_, 64); a0.y += __shfl_xor(a0.y, m_, 64); \
    a0.z += __shfl_xor(a0.z, m_, 64); a0.w += __shfl_xor(a0.w, m_, 64); \
    a1.x += __shfl_xor(a1.x, m_, 64); a1.y += __shfl_xor(a1.y, m_, 64); \
    a1.z += __shfl_xor(a1.z, m_, 64); a1.w += __shfl_xor(a1.w, m_, 64); \
    a2.x += __shfl_xor(a2.x, m_, 64); a2.y += __shfl_xor(a2.y, m_, 64); \
    a2.z += __shfl_xor(a2.z, m_, 64); a2.w += __shfl_xor(a2.w, m_, 64); \
    a3.x += __shfl_xor(a3.x, m_, 64); a3.y += __shfl_xor(a3.y, m_, 64); \
    a3.z += __shfl_xor(a3.z, m_, 64); a3.w += __shfl_xor(a3.w, m_, 64);
    GRED(16)
    GRED(32)
#undef GRED

    // Block reduction across the 4 waves.
    __shared__ float lds[WAVES_PER_BLOCK][D];
    if (g == 0) {
        // lane sub's acc[m] covers dims [4*sub + 64*m, +4)
        *(float4*)&lds[w][4 * sub      ] = a0;
        *(float4*)&lds[w][4 * sub +  64] = a1;
        *(float4*)&lds[w][4 * sub + 128] = a2;
        *(float4*)&lds[w][4 * sub + 192] = a3;
    }
    __syncthreads();

    const int t = threadIdx.x;
    const float val = lds[0][t] + lds[1][t] + lds[2][t] + lds[3][t];
    if (USE_PARTIALS) {
        sums[(size_t)blockIdx.x * D + t] = val;     // no atomics, no memset
    } else {
        atomicAdd(&sums[(size_t)pair * D + t], val);
    }
}

// ---- Kernel 2 (partials path): per batch, reduce 64-block partials for both
// inputs, dot them, block-reduce, write 1 - dot/S^2.
__global__ __launch_bounds__(256) void finalize_partials_kernel(
    const float* __restrict__ partials, float* __restrict__ out)
{
    const int b = blockIdx.x;
    const int t = threadIdx.x;
    const int w = t >> 6, lane = t & 63;

    const float* p1 = partials + ((size_t)(2 * b + 0) * BLOCKS_PER_PAIR) * D + t;
    const float* p2 = partials + ((size_t)(2 * b + 1) * BLOCKS_PER_PAIR) * D + t;
    float s1 = 0.f, s2 = 0.f;
    #pragma unroll 8
    for (int k = 0; k < BLOCKS_PER_PAIR; ++k) {
        s1 += p1[(size_t)k * D];
        s2 += p2[(size_t)k * D];
    }
    float d = s1 * s2;
    #pragma unroll
    for (int m = 1; m < 64; m <<= 1) d += __shfl_xor(d, m, 64);

    __shared__ float r[WAVES_PER_BLOCK];
    if (lane == 0) r[w] = d;
    __syncthreads();
    if (t == 0) {
        const float inv = 1.0f / ((float)S * (float)S);
        out[b] = 1.0f - (r[0] + r[1] + r[2] + r[3]) * inv;
    }
}

// ---- Kernel 2 (atomic fallback path): sums are already fully reduced.
__global__ __launch_bounds__(64) void finalize_kernel(
    const float* __restrict__ sums, float* __restrict__ out)
{
    const int b = blockIdx.x;
    const int lane = threadIdx.x;
    const float4 a = *(const float4*)(sums + (size_t)(2 * b + 0) * D + lane * 4);
    const float4 c = *(const float4*)(sums + (size_t)(2 * b + 1) * D + lane * 4);
    float d = a.x * c.x + a.y * c.y + a.z * c.z + a.w * c.w;
    #pragma unroll
    for (int m = 1; m < 64; m <<= 1) d += __shfl_xor(d, m, 64);
    if (lane == 0) {
        const float inv = 1.0f / ((float)S * (float)S);
        out[b] = 1.0f - d * inv;
    }
}

extern "C" void kernel_launch(void* const* d_in, const int* in_sizes, int n_in,
                              void* d_out, int out_size, void* d_ws, size_t ws_size,
                              hipStream_t stream) {
    const float* x1 = (const float*)d_in[0];
    const float* x2 = (const float*)d_in[1];
    float* out = (float*)d_out;
    float* ws = (float*)d_ws;

    const size_t partial_bytes = (size_t)NBLK1 * D * sizeof(float);   // 2 MB
    if (ws_size >= partial_bytes) {
        row_norm_sum_kernel<true><<<NBLK1, 256, 0, stream>>>(x1, x2, ws);
        finalize_partials_kernel<<<B, 256, 0, stream>>>(ws, out);
    } else {
        hipMemsetAsync(ws, 0, (size_t)NPAIR * D * sizeof(float), stream);
        row_norm_sum_kernel<false><<<NBLK1, 256, 0, stream>>>(x1, x2, ws);
        finalize_kernel<<<B, 64, 0, stream>>>(ws, out);
    }
}